// Round 6
// baseline (1112.251 us; speedup 1.0000x reference)
//
#include <hip/hip_runtime.h>
#include <stdint.h>

typedef unsigned short u16;
typedef short v8s __attribute__((ext_vector_type(8)));
typedef short v4s __attribute__((ext_vector_type(4)));
typedef float v4f __attribute__((ext_vector_type(4)));

#define NB 32768
#define ND 256
#define DTF (1.0f/3.0f)
#define ALPHA 0.1f
#define DECAY 0.99f
#define TAU_MIN 0.2f
#define HEBB_SCALE (0.1f*(1.0f/3.0f)/32768.0f)

__device__ __forceinline__ float b2f(u16 h){ return __uint_as_float(((unsigned)h)<<16); }
__device__ __forceinline__ u16 f2b(float f){
  unsigned u = __float_as_uint(f);
  u += 0x7FFFu + ((u>>16)&1u);
  return (u16)(u>>16);
}

__device__ __forceinline__ void async16(const void* g, void* l){
  __builtin_amdgcn_global_load_lds((const __attribute__((address_space(1))) unsigned*)g,
                                   (__attribute__((address_space(3))) unsigned*)l, 16, 0, 0);
}

__device__ __forceinline__ void waitv(int n){
  switch(n){
    case 12: asm volatile("s_waitcnt vmcnt(12)" ::: "memory"); break;
    case 9:  asm volatile("s_waitcnt vmcnt(9)"  ::: "memory"); break;
    case 8:  asm volatile("s_waitcnt vmcnt(8)"  ::: "memory"); break;
    case 6:  asm volatile("s_waitcnt vmcnt(6)"  ::: "memory"); break;
    case 4:  asm volatile("s_waitcnt vmcnt(4)"  ::: "memory"); break;
    case 3:  asm volatile("s_waitcnt vmcnt(3)"  ::: "memory"); break;
    case 2:  asm volatile("s_waitcnt vmcnt(2)"  ::: "memory"); break;
    default: asm volatile("s_waitcnt vmcnt(0)"  ::: "memory"); break;
  }
}

// ---------------- init: x,h -> bf16; x -> xT (fused) ----------------
__global__ void k_init(const float* __restrict__ x, const float* __restrict__ h,
                       u16* __restrict__ x_bf, u16* __restrict__ h_bf,
                       u16* __restrict__ xT){
  __shared__ u16 lt[256*68];          // [col][row] bf16 staging for transpose
  const long r0 = (long)blockIdx.x*64;
  const int t = threadIdx.x;
#pragma unroll
  for (int e=0; e<16; ++e){
    int i = e*1024 + t*4;             // 0..16383 over [64][256]
    int row = i>>8, col = i&255;
    v4f xv = *(const v4f*)(x + (r0+row)*ND + col);
    v4f hv = *(const v4f*)(h + (r0+row)*ND + col);
    u16 a4[4], b4[4];
#pragma unroll
    for (int k=0;k<4;++k){ a4[k]=f2b(xv[k]); b4[k]=f2b(hv[k]); }
    *(v4s*)(x_bf + (r0+row)*ND + col) = *(v4s*)a4;
    *(v4s*)(h_bf + (r0+row)*ND + col) = *(v4s*)b4;
#pragma unroll
    for (int k=0;k<4;++k) lt[(col+k)*68 + row] = a4[k];
  }
  __syncthreads();
#pragma unroll
  for (int e=0; e<16; ++e)
    *(v4s*)(xT + (long)t*NB + r0 + e*4) = *(v4s*)&lt[t*68 + e*4];
}

// ---------------- weight prep (bf16 [n][k]) ----------------
__global__ void k_prep_w(const float* __restrict__ W_ih, const float* __restrict__ W_hh,
                         const float* __restrict__ W_t1, const float* __restrict__ W_t2,
                         const float* __restrict__ hebb_ih, const float* __restrict__ hebb_hh,
                         u16* __restrict__ weff_ih, u16* __restrict__ weff_hh,
                         u16* __restrict__ wt1a, u16* __restrict__ wt1b, u16* __restrict__ wt2){
  int i = blockIdx.x*blockDim.x + threadIdx.x;
  if (i >= ND*ND) return;
  int n = i >> 8, k = i & 255;
  weff_ih[i] = f2b(W_ih[i] + ALPHA*hebb_ih[k*ND + n]);
  weff_hh[i] = f2b(W_hh[i] + ALPHA*hebb_hh[k*ND + n]);
  wt1a[i] = f2b(W_t1[n*512 + k]);
  wt1b[i] = f2b(W_t1[n*512 + 256 + k]);
  wt2[i]  = f2b(W_t2[i]);
}

// ---------------- P = x @ W_t1a^T + b_t1  (bf16 out) ----------------
__launch_bounds__(512,2)
__global__ void k_gemmP(const u16* __restrict__ x_bf, const u16* __restrict__ wt1a,
                        const float* __restrict__ b_t1, u16* __restrict__ P){
  __shared__ u16 lA[128*40];
  __shared__ u16 lB[256*40];
  int t = threadIdx.x, lid = t&63, wid = t>>6, wm = wid>>2, wn = wid&3, lr = lid&15, lg = lid>>4;
  long row0 = (long)blockIdx.x*128;
  v4f z = {0.f,0.f,0.f,0.f};
  v4f acc[4][4];
#pragma unroll
  for (int a=0;a<4;++a)
#pragma unroll
    for (int b=0;b<4;++b) acc[a][b] = z;
  for (int c=0; c<8; ++c){
    __syncthreads();
    { int r=t>>2, sg=t&3;
      *(v8s*)&lA[r*40+sg*8] = *(const v8s*)(x_bf + (row0+r)*ND + c*32 + sg*8); }
#pragma unroll
    for (int it2=0; it2<2; ++it2){
      int s2=t+it2*512; int n=s2>>2, sg=s2&3;
      *(v8s*)&lB[n*40+sg*8] = *(const v8s*)(wt1a + n*ND + c*32 + sg*8);
    }
    __syncthreads();
    v8s a[4], b[4];
#pragma unroll
    for (int mf=0;mf<4;++mf) a[mf] = *(v8s*)&lA[(wm*64+mf*16+lr)*40 + lg*8];
#pragma unroll
    for (int nf=0;nf<4;++nf) b[nf] = *(v8s*)&lB[(wn*64+nf*16+lr)*40 + lg*8];
#pragma unroll
    for (int mf=0;mf<4;++mf)
#pragma unroll
      for (int nf=0;nf<4;++nf)
        acc[mf][nf] = __builtin_amdgcn_mfma_f32_16x16x32_bf16(a[mf], b[nf], acc[mf][nf], 0,0,0);
  }
#pragma unroll
  for (int mf=0;mf<4;++mf)
#pragma unroll
    for (int nf=0;nf<4;++nf)
#pragma unroll
      for (int r=0;r<4;++r){
        int rr = wm*64+mf*16+lg*4+r, cc = wn*64+nf*16+lr;
        P[(row0+rr)*ND + cc] = f2b(acc[mf][nf][r] + b_t1[cc]);
      }
}

// ---------------- fused dynamics + RK update (rolled, deep-pipelined) --------
// jobs 0-7: ev@wt1b -> acc2 ; 8-15: x@weff_ih -> accI ; 16-23: ev@weff_hh -> accI
// 24-31: u@wt2 -> acc4 (u from lU; A-ring gets dummy x stages to keep rates uniform)
template<int BASEF, int WF, int WT, int WB>
__launch_bounds__(512,2)
__global__ void k_dyn3(const u16* __restrict__ x_bf, const u16* __restrict__ ev_bf,
                       const float* __restrict__ baseF,
                       const u16* __restrict__ weff_ih, const u16* __restrict__ weff_hh,
                       const u16* __restrict__ wt1b, const u16* __restrict__ wt2,
                       const u16* __restrict__ P,
                       const float* __restrict__ b_ih, const float* __restrict__ b_hh,
                       const float* __restrict__ b_t2, float coef,
                       float* __restrict__ outF, u16* __restrict__ outB, u16* __restrict__ outT){
  __shared__ u16 lA[5*2048];       // 5 x [64][32] linear (gload_lds dest)
  __shared__ u16 lB[5*8192];       // 5 x [256][32] linear
  __shared__ u16 lU[64*272];       // u panel [64][272] (chunk-XOR); reused [256][68] for WT
  __shared__ float sb1[256], sb2[256];
  const int t = threadIdx.x, lid = t&63, wid = t>>6;
  const int wm = wid>>2, wn = wid&3, lr = lid&15, lg = lid>>4;
  const long row0 = (long)blockIdx.x*64;

  if (t < 256){ sb1[t] = b_ih[t] + b_hh[t]; sb2[t] = b_t2[t]; }

  // staging source offsets (chunk-XOR pre-swizzled on the GLOBAL side)
  const int rA  = (wid&3)*16 + (lid>>2);
  const long aoffg = (row0 + rA)*ND + (((lid&3) ^ ((rA>>1)&3))*8);
  const int rB0 = wid*32 + (lid>>2), rB1 = rB0 + 16;
  const int boffg0 = rB0*ND + (((lid&3) ^ ((rB0>>1)&3))*8);
  const int boffg1 = rB1*ND + (((lid&3) ^ ((rB1>>1)&3))*8);

  // fragment read offsets (u16 index within a slot), same XOR on the read side
  int aoff[2], boff[4], uoff[2];
#pragma unroll
  for (int mf=0;mf<2;++mf){
    int R = wm*32 + mf*16 + lr;
    aoff[mf] = R*32 + ((lg ^ ((R>>1)&3))*8);
    uoff[mf] = R*272 + ((lg ^ ((R>>1)&3))*8);
  }
#pragma unroll
  for (int nf=0;nf<4;++nf){
    int N = wn*64 + nf*16 + lr;
    boff[nf] = N*32 + ((lg ^ ((N>>1)&3))*8);
  }

  auto stage = [&](int jj, int sl){
    const u16* asrc = (jj<8) ? ev_bf : (jj<16 ? x_bf : (jj<24 ? ev_bf : x_bf)); // >=24 dummy
    const u16* W    = (jj<8) ? wt1b  : (jj<16 ? weff_ih : (jj<24 ? weff_hh : wt2));
    const int c = (jj&7)*32;
    if (wid < 4) async16(asrc + aoffg + c, lA + sl*2048 + (wid&3)*512);
    async16(W + c + boffg0, lB + sl*8192 + wid*1024);
    async16(W + c + boffg1, lB + sl*8192 + wid*1024 + 512);
  };

  // prologue: stages 0-3, then P prefetch, then full drain
  stage(0,0); stage(1,1); stage(2,2); stage(3,3);
  u16 Pv[32];
#pragma unroll
  for (int mf=0;mf<2;++mf)
#pragma unroll
    for (int nf=0;nf<4;++nf)
#pragma unroll
      for (int r=0;r<4;++r){
        int rr = wm*32+mf*16+lg*4+r, cc = wn*64+nf*16+lr;
        Pv[(mf*4+nf)*4+r] = P[(row0+rr)*ND + cc];
      }
  __syncthreads();

  v4f z = {0.f,0.f,0.f,0.f};
  v4f acc2[2][4], accI[2][4], acc4[2][4];
#pragma unroll
  for (int a=0;a<2;++a)
#pragma unroll
    for (int b=0;b<4;++b){ acc2[a][b]=z; accI[a][b]=z; acc4[a][b]=z; }

  int rs = 0, wsl = 4;
  for (int j=0; j<32; ++j){
    int m3 = 31-j; if (m3 > 3) m3 = 3;
    waitv(m3 * (wid<4 ? 3 : 2));
    __builtin_amdgcn_s_barrier();
    if (j <= 27) stage(j+4, wsl);

    v8s b[4];
#pragma unroll
    for (int nf=0;nf<4;++nf) b[nf] = *(v8s*)&lB[rs*8192 + boff[nf]];
    v8s a[2];
    if (j < 24){
#pragma unroll
      for (int mf=0;mf<2;++mf) a[mf] = *(v8s*)&lA[rs*2048 + aoff[mf]];
    } else {
#pragma unroll
      for (int mf=0;mf<2;++mf) a[mf] = *(v8s*)&lU[uoff[mf] + (j&7)*32];
    }

    __builtin_amdgcn_s_setprio(1);
    if (j < 8){
#pragma unroll
      for (int mf=0;mf<2;++mf)
#pragma unroll
        for (int nf=0;nf<4;++nf)
          acc2[mf][nf] = __builtin_amdgcn_mfma_f32_16x16x32_bf16(a[mf], b[nf], acc2[mf][nf], 0,0,0);
    } else if (j < 24){
#pragma unroll
      for (int mf=0;mf<2;++mf)
#pragma unroll
        for (int nf=0;nf<4;++nf)
          accI[mf][nf] = __builtin_amdgcn_mfma_f32_16x16x32_bf16(a[mf], b[nf], accI[mf][nf], 0,0,0);
    } else {
#pragma unroll
      for (int mf=0;mf<2;++mf)
#pragma unroll
        for (int nf=0;nf<4;++nf)
          acc4[mf][nf] = __builtin_amdgcn_mfma_f32_16x16x32_bf16(a[mf], b[nf], acc4[mf][nf], 0,0,0);
    }
    __builtin_amdgcn_s_setprio(0);

    if (j == 7){
      // u = SiLU(acc2 + P) -> lU [64][272] with chunk-XOR per row-pair
#pragma unroll
      for (int mf=0;mf<2;++mf)
#pragma unroll
        for (int nf=0;nf<4;++nf)
#pragma unroll
          for (int r=0;r<4;++r){
            int rr = wm*32+mf*16+lg*4+r, cc = wn*64+nf*16+lr;
            float v = acc2[mf][nf][r] + b2f(Pv[(mf*4+nf)*4+r]);
            float sgm = 1.f/(1.f + __expf(-v));
            int w = cc>>5, ch = (cc>>3)&3;
            lU[rr*272 + w*32 + ((ch ^ ((rr>>1)&3))*8) + (cc&7)] = f2b(v*sgm);
          }
      asm volatile("s_waitcnt lgkmcnt(0)" ::: "memory");
    }
    rs = (rs==4)?0:rs+1; wsl = (wsl==4)?0:wsl+1;
  }

  __syncthreads();   // all lU phase-4 reads done (before WT reuse)

  // epilogue: inter = tanh(accI + b), tau = softplus(acc4 + b_t2) + TAU_MIN
#pragma unroll
  for (int mf=0;mf<2;++mf)
#pragma unroll
    for (int nf=0;nf<4;++nf)
#pragma unroll
      for (int r=0;r<4;++r){
        int rr = wm*32+mf*16+lg*4+r, cc = wn*64+nf*16+lr;
        long gi = (row0+rr)*ND + cc;
        float pre = accI[mf][nf][r] + sb1[cc];
        float pc = fminf(fmaxf(pre, -15.f), 15.f);
        float e2 = __expf(2.f*pc);
        float inter = (e2 - 1.f)/(e2 + 1.f);
        float zz = acc4[mf][nf][r] + sb2[cc];
        float sp = (zz > 15.f) ? zz : __logf(1.f + __expf(zz));
        float tau = sp + TAU_MIN;
        float bv, ev;
        if (BASEF){ bv = baseF[gi]; ev = b2f(ev_bf[gi]); }
        else      { bv = b2f(ev_bf[gi]); ev = bv; }
        float o = bv + coef*(inter - ev)/tau;
        if (WF) outF[gi] = o;
        if (WB) outB[gi] = f2b(o);
        if (WT) lU[cc*68 + rr] = f2b(o);
      }
  if (WT){
    __syncthreads();
    int cc = t>>1, r0b = (t&1)*32;
#pragma unroll
    for (int e=0;e<8;++e)
      *(v4s*)(outT + (long)cc*NB + row0 + r0b + e*4) = *(v4s*)&lU[cc*68 + r0b + e*4];
  }
}

// ---------------- hebb partial: part[blk] = A^T-chunk @ hm-chunk (pipelined) --
__launch_bounds__(512,2)
__global__ void k_hebb_part2(const u16* __restrict__ xT, const u16* __restrict__ hmT,
                             u16* __restrict__ part){
  __shared__ u16 lA[4*8192];    // 4 x [256][32]
  __shared__ u16 lB[4*8192];
  const int t = threadIdx.x, lid = t&63, wid = t>>6;
  const int wm = wid>>2, wn = wid&3, lr = lid&15, lg = lid>>4;
  const int mat = blockIdx.x & 1, chunk = blockIdx.x >> 1;   // 128 chunks x 2 mats
  const u16* Asrc = mat ? hmT : xT;
  const long col0 = (long)chunk*256;

  const int r0s = wid*32 + (lid>>2), r1s = r0s + 16;
  const long goff0 = (long)r0s*NB + (((lid&3) ^ ((r0s>>1)&3))*8);
  const long goff1 = (long)r1s*NB + (((lid&3) ^ ((r1s>>1)&3))*8);

  int aoff[8], boff[4];
#pragma unroll
  for (int mf=0;mf<8;++mf){
    int R = wm*128 + mf*16 + lr;
    aoff[mf] = R*32 + ((lg ^ ((R>>1)&3))*8);
  }
#pragma unroll
  for (int nf=0;nf<4;++nf){
    int N = wn*64 + nf*16 + lr;
    boff[nf] = N*32 + ((lg ^ ((N>>1)&3))*8);
  }

  auto stage = [&](int kc, int sl){
    const long c = col0 + kc*32;
    async16(Asrc + goff0 + c, lA + sl*8192 + wid*1024);
    async16(Asrc + goff1 + c, lA + sl*8192 + wid*1024 + 512);
    async16(hmT  + goff0 + c, lB + sl*8192 + wid*1024);
    async16(hmT  + goff1 + c, lB + sl*8192 + wid*1024 + 512);
  };

  stage(0,0); stage(1,1); stage(2,2);
  __syncthreads();

  v4f z = {0.f,0.f,0.f,0.f};
  v4f acc[8][4];
#pragma unroll
  for (int a=0;a<8;++a)
#pragma unroll
    for (int b=0;b<4;++b) acc[a][b] = z;

  for (int j=0; j<8; ++j){
    int m2 = 7-j; if (m2 > 2) m2 = 2;
    waitv(m2*4);
    __builtin_amdgcn_s_barrier();
    if (j <= 4) stage(j+3, (j+3)&3);
    const int rs = j&3;
    v8s a[8], b[4];
#pragma unroll
    for (int mf=0;mf<8;++mf) a[mf] = *(v8s*)&lA[rs*8192 + aoff[mf]];
#pragma unroll
    for (int nf=0;nf<4;++nf) b[nf] = *(v8s*)&lB[rs*8192 + boff[nf]];
    __builtin_amdgcn_s_setprio(1);
#pragma unroll
    for (int mf=0;mf<8;++mf)
#pragma unroll
      for (int nf=0;nf<4;++nf)
        acc[mf][nf] = __builtin_amdgcn_mfma_f32_16x16x32_bf16(a[mf], b[nf], acc[mf][nf], 0,0,0);
    __builtin_amdgcn_s_setprio(0);
  }

  u16* dst = part + (long)blockIdx.x*65536;
#pragma unroll
  for (int mf=0;mf<8;++mf)
#pragma unroll
    for (int nf=0;nf<4;++nf)
#pragma unroll
      for (int r=0;r<4;++r){
        int i = wm*128+mf*16+lg*4+r, jj = wn*64+nf*16+lr;
        dst[i*ND + jj] = f2b(acc[mf][nf][r]);
      }
}

// ---------------- hebb reduce + Weff rebuild ----------------
__global__ void k_hebb_reduce(const u16* __restrict__ part,
                              const float* __restrict__ prev_ih, const float* __restrict__ prev_hh,
                              float* __restrict__ next_ih, float* __restrict__ next_hh,
                              const float* __restrict__ W_ih, const float* __restrict__ W_hh,
                              u16* __restrict__ weff_ih, u16* __restrict__ weff_hh){
  int tid = blockIdx.x*blockDim.x + threadIdx.x;
  if (tid >= 2*ND*ND) return;
  int mat = tid >> 16;
  int rem = tid & 65535;
  float s = 0.f;
  for (int c=0; c<128; ++c) s += b2f(part[(long)((c<<1)+mat)*65536 + rem]);
  const float* prev = mat ? prev_hh : prev_ih;
  float nv = DECAY*prev[rem] + HEBB_SCALE*s;
  if (mat) next_hh[rem] = nv; else next_ih[rem] = nv;
  int k = rem >> 8, n = rem & 255;
  const float* Wb = mat ? W_hh : W_ih;
  u16 wv = f2b(Wb[n*ND + k] + ALPHA*nv);
  if (mat) weff_hh[n*ND + k] = wv; else weff_ih[n*ND + k] = wv;
}

// ---------------- launcher ----------------
extern "C" void kernel_launch(void* const* d_in, const int* in_sizes, int n_in,
                              void* d_out, int out_size, void* d_ws, size_t ws_size,
                              hipStream_t stream) {
  const float* x       = (const float*)d_in[0];
  const float* h       = (const float*)d_in[1];
  const float* hebb_ih = (const float*)d_in[2];
  const float* hebb_hh = (const float*)d_in[3];
  const float* W_ih    = (const float*)d_in[4];
  const float* b_ih    = (const float*)d_in[5];
  const float* W_hh    = (const float*)d_in[6];
  const float* b_hh    = (const float*)d_in[7];
  const float* W_t1    = (const float*)d_in[8];
  const float* b_t1    = (const float*)d_in[9];
  const float* W_t2    = (const float*)d_in[10];
  const float* b_t2    = (const float*)d_in[11];
  float* h_state = (float*)d_out;

  char* w = (char*)d_ws;
  u16* x_bf  = (u16*)w;  w += 16777216;
  u16* xT    = (u16*)w;  w += 16777216;
  u16* P     = (u16*)w;  w += 16777216;
  u16* hmT   = (u16*)w;  w += 16777216;
  u16* h_bf  = (u16*)w;  w += 16777216;
  u16* hm_bf = (u16*)w;  w += 16777216;
  u16* part  = (u16*)w;  w += 33554432;     // 256 slabs x 64K x 2B
  float* hebA_ih = (float*)w; w += 262144;
  float* hebA_hh = (float*)w; w += 262144;
  float* hebB_ih = (float*)w; w += 262144;
  float* hebB_hh = (float*)w; w += 262144;
  u16* weff_ih = (u16*)w; w += 131072;
  u16* weff_hh = (u16*)w; w += 131072;
  u16* wt1a    = (u16*)w; w += 131072;
  u16* wt1b    = (u16*)w; w += 131072;
  u16* wt2     = (u16*)w; w += 131072;
  if ((size_t)(w - (char*)d_ws) > ws_size) return;

  k_init<<<512,256,0,stream>>>(x, h, x_bf, h_bf, xT);
  k_prep_w<<<256,256,0,stream>>>(W_ih,W_hh,W_t1,W_t2,hebb_ih,hebb_hh,
                                 weff_ih,weff_hh,wt1a,wt1b,wt2);
  k_gemmP<<<256,512,0,stream>>>(x_bf, wt1a, b_t1, P);

  const float* pih = hebb_ih; const float* phh = hebb_hh;
  for (int s=0; s<3; ++s){
    float* nih = (s&1) ? hebB_ih : hebA_ih;
    float* nhh = (s&1) ? hebB_hh : hebA_hh;
    // k1: h_mid = h + 0.5*DT*dynamics(h)  (bf16 state path; writes hm_bf + hmT)
    k_dyn3<0,0,1,1><<<512,512,0,stream>>>(x_bf, h_bf, (const float*)0,
                                          weff_ih, weff_hh, wt1b, wt2, P,
                                          b_ih, b_hh, b_t2, 0.5f*DTF,
                                          (float*)0, hm_bf, hmT);
    // hebb updates + Weff rebuild
    k_hebb_part2<<<256,512,0,stream>>>(xT, hmT, part);
    k_hebb_reduce<<<512,256,0,stream>>>(part, pih, phh, nih, nhh, W_ih, W_hh, weff_ih, weff_hh);
    // k2: h = h + DT*dynamics(h_mid)  (baseF = h input on step 0, else h_state)
    const float* base = (s==0) ? h : (const float*)h_state;
    if (s < 2)
      k_dyn3<1,1,0,1><<<512,512,0,stream>>>(x_bf, hm_bf, base,
                                            weff_ih, weff_hh, wt1b, wt2, P,
                                            b_ih, b_hh, b_t2, DTF,
                                            h_state, h_bf, (u16*)0);
    else
      k_dyn3<1,1,0,0><<<512,512,0,stream>>>(x_bf, hm_bf, base,
                                            weff_ih, weff_hh, wt1b, wt2, P,
                                            b_ih, b_hh, b_t2, DTF,
                                            h_state, (u16*)0, (u16*)0);
    pih = nih; phh = nhh;
  }
}